// Round 1
// baseline (440.093 us; speedup 1.0000x reference)
//
#include <hip/hip_runtime.h>
#include <hip/hip_bf16.h>

typedef __attribute__((ext_vector_type(8))) short short8_t;
typedef __attribute__((ext_vector_type(4))) float f32x4;
typedef __attribute__((ext_vector_type(4))) unsigned int u32x4;

#define KINST 100000
#define KPAD  100096   // 782 * 128
#define DIMIN 768
#define DIMEMB 512
#define DIMATTN 384

__device__ __forceinline__ unsigned short f2bf(float f) {
    unsigned int u = __builtin_bit_cast(unsigned int, f);
    u = u + 0x7FFFu + ((u >> 16) & 1u);       // RNE
    return (unsigned short)(u >> 16);
}
__device__ __forceinline__ float bf2f(unsigned short h) {
    unsigned int u = ((unsigned int)h) << 16;
    return __builtin_bit_cast(float, u);
}

// ---------------- prep: transposed bf16 weights ----------------
__global__ __launch_bounds__(256) void k_prep(
    const float* __restrict__ Wproj, const float* __restrict__ W1,
    unsigned short* __restrict__ WpT, unsigned short* __restrict__ W1T)
{
    const int idx = blockIdx.x * 256 + threadIdx.x;
    if (idx < DIMEMB * DIMIN) {
        const int n = idx / DIMIN, k = idx % DIMIN;
        WpT[idx] = f2bf(Wproj[(size_t)k * DIMEMB + n]);
    } else {
        const int j = idx - DIMEMB * DIMIN;
        if (j < DIMATTN * DIMEMB) {
            const int n = j / DIMEMB, k = j % DIMEMB;
            W1T[j] = f2bf(W1[(size_t)k * DIMATTN + n]);
        }
    }
}

// ---------------- GEMM1: H = relu(X @ Wp + b), bf16 out ----------------
__global__ __launch_bounds__(256) void k_gemm1(
    const float* __restrict__ X,
    const unsigned short* __restrict__ WpT,
    const float* __restrict__ bproj,
    unsigned short* __restrict__ H)
{
    __shared__ unsigned short As[128][72];   // +8 pad -> 2-way bank alias (free)
    __shared__ unsigned short Bs[128][72];
    const int tid = threadIdx.x;
    const int lane = tid & 63, w = tid >> 6;
    const int wr = w >> 1, wc = w & 1;       // 2x2 waves, 64x64 each
    const int brow = blockIdx.x * 128;
    const int bcol = blockIdx.y * 128;

    f32x4 acc[4][4] = {};

    for (int k0 = 0; k0 < DIMIN; k0 += 64) {
        {   // stage A: X fp32 -> bf16, 128x64
            const int c4 = (tid & 15) << 2;
            const int r0 = tid >> 4;
            #pragma unroll
            for (int p = 0; p < 8; ++p) {
                const int r = p * 16 + r0;
                int gr = brow + r; gr = gr < KINST ? gr : (KINST - 1);
                const float4 v = *reinterpret_cast<const float4*>(X + (size_t)gr * DIMIN + k0 + c4);
                ushort4 b;
                b.x = f2bf(v.x); b.y = f2bf(v.y); b.z = f2bf(v.z); b.w = f2bf(v.w);
                *reinterpret_cast<ushort4*>(&As[r][c4]) = b;
            }
        }
        {   // stage B: WpT bf16, 128x64
            const int ch = (tid & 7) << 3;
            const int r0 = tid >> 3;
            #pragma unroll
            for (int p = 0; p < 4; ++p) {
                const int r = p * 32 + r0;
                const u32x4 v = *reinterpret_cast<const u32x4*>(WpT + (size_t)(bcol + r) * DIMIN + k0 + ch);
                *reinterpret_cast<u32x4*>(&Bs[r][ch]) = v;
            }
        }
        __syncthreads();
        #pragma unroll
        for (int kk = 0; kk < 64; kk += 32) {
            const int krd = kk + ((lane >> 4) << 3);
            short8_t af[4], bfr[4];
            #pragma unroll
            for (int i = 0; i < 4; ++i)
                af[i] = *reinterpret_cast<const short8_t*>(&As[wr * 64 + i * 16 + (lane & 15)][krd]);
            #pragma unroll
            for (int j = 0; j < 4; ++j)
                bfr[j] = *reinterpret_cast<const short8_t*>(&Bs[wc * 64 + j * 16 + (lane & 15)][krd]);
            #pragma unroll
            for (int i = 0; i < 4; ++i)
                #pragma unroll
                for (int j = 0; j < 4; ++j)
                    acc[i][j] = __builtin_amdgcn_mfma_f32_16x16x32_bf16(af[i], bfr[j], acc[i][j], 0, 0, 0);
        }
        __syncthreads();
    }

    #pragma unroll
    for (int j = 0; j < 4; ++j) {
        const int col = bcol + wc * 64 + j * 16 + (lane & 15);
        const float bias = bproj[col];
        #pragma unroll
        for (int i = 0; i < 4; ++i) {
            const int rb = brow + wr * 64 + i * 16 + ((lane >> 4) << 2);
            #pragma unroll
            for (int r = 0; r < 4; ++r) {
                float v = fmaxf(acc[i][j][r] + bias, 0.f);
                const int row = rb + r;
                H[(size_t)row * DIMEMB + col] = (row < KINST) ? f2bf(v) : (unsigned short)0;
            }
        }
    }
}

// -------- GEMM2 + attention score: E = exp(tanh(H@W1+b1)@W2+b2) --------
__global__ __launch_bounds__(512) void k_gemm2(
    const unsigned short* __restrict__ H,
    const unsigned short* __restrict__ W1T,
    const float* __restrict__ b1,
    const float* __restrict__ W2,
    const float* __restrict__ b2,
    float* __restrict__ E,
    float* __restrict__ Spart)
{
    __shared__ unsigned short Hs[128][40];
    __shared__ unsigned short Bs[384][40];
    __shared__ float sred[4][128];
    __shared__ float ssum[8];
    const int tid = threadIdx.x;
    const int lane = tid & 63, w = tid >> 6;
    const int wr = w >> 2, wc = w & 3;       // 2x4 waves: 64 rows x 96 cols each
    const int brow = blockIdx.x * 128;

    f32x4 acc[4][6] = {};

    for (int k0 = 0; k0 < DIMEMB; k0 += 32) {
        {   // Hs: 128x32 bf16 (1 chunk/thread)
            const int ch = (tid & 3) << 3;
            const int r = tid >> 2;
            const u32x4 v = *reinterpret_cast<const u32x4*>(H + (size_t)(brow + r) * DIMEMB + k0 + ch);
            *reinterpret_cast<u32x4*>(&Hs[r][ch]) = v;
        }
        {   // Bs: 384x32 bf16 (3 chunks/thread)
            const int ch = (tid & 3) << 3;
            const int r0 = tid >> 2;
            #pragma unroll
            for (int p = 0; p < 3; ++p) {
                const int r = p * 128 + r0;
                const u32x4 v = *reinterpret_cast<const u32x4*>(W1T + (size_t)r * DIMEMB + k0 + ch);
                *reinterpret_cast<u32x4*>(&Bs[r][ch]) = v;
            }
        }
        __syncthreads();
        const int krd = (lane >> 4) << 3;
        short8_t af[4];
        #pragma unroll
        for (int i = 0; i < 4; ++i)
            af[i] = *reinterpret_cast<const short8_t*>(&Hs[wr * 64 + i * 16 + (lane & 15)][krd]);
        #pragma unroll
        for (int j = 0; j < 6; ++j) {
            const short8_t bfr = *reinterpret_cast<const short8_t*>(&Bs[wc * 96 + j * 16 + (lane & 15)][krd]);
            #pragma unroll
            for (int i = 0; i < 4; ++i)
                acc[i][j] = __builtin_amdgcn_mfma_f32_16x16x32_bf16(af[i], bfr, acc[i][j], 0, 0, 0);
        }
        __syncthreads();
    }

    // epilogue: per-lane partial score over this wave's 96 cols
    float ps[4][4] = {};
    #pragma unroll
    for (int j = 0; j < 6; ++j) {
        const int col = wc * 96 + j * 16 + (lane & 15);
        const float bb = b1[col], ww = W2[col];
        #pragma unroll
        for (int i = 0; i < 4; ++i)
            #pragma unroll
            for (int r = 0; r < 4; ++r)
                ps[i][r] += tanhf(acc[i][j][r] + bb) * ww;
    }
    #pragma unroll
    for (int off = 1; off < 16; off <<= 1)
        #pragma unroll
        for (int i = 0; i < 4; ++i)
            #pragma unroll
            for (int r = 0; r < 4; ++r)
                ps[i][r] += __shfl_xor(ps[i][r], off, 64);
    if ((lane & 15) == 0) {
        #pragma unroll
        for (int i = 0; i < 4; ++i)
            #pragma unroll
            for (int r = 0; r < 4; ++r)
                sred[wc][wr * 64 + i * 16 + ((lane >> 4) << 2) + r] = ps[i][r];
    }
    __syncthreads();
    float myE = 0.f;
    if (tid < 128) {
        const int row = brow + tid;
        const float s = sred[0][tid] + sred[1][tid] + sred[2][tid] + sred[3][tid] + b2[0];
        const float e = expf(s);
        if (row < KINST) { E[row] = e; myE = e; }
    }
    #pragma unroll
    for (int off = 1; off < 64; off <<= 1) myE += __shfl_xor(myE, off, 64);
    if (lane == 0) ssum[w] = myE;
    __syncthreads();
    if (tid == 0) {
        float t = 0.f;
        #pragma unroll
        for (int i = 0; i < 8; ++i) t += ssum[i];
        Spart[blockIdx.x] = t;
    }
}

// ---------------- pooling: Mpart[b][d] = sum_k E_k * H_kd ----------------
__global__ __launch_bounds__(512) void k_pool(
    const unsigned short* __restrict__ H,
    const float* __restrict__ E,
    float* __restrict__ Mpart)
{
    __shared__ float red[8][512];
    const int tid = threadIdx.x, lane = tid & 63, w = tid >> 6;
    const int base = blockIdx.x * 1024;
    float a[8] = {};
    for (int i = 0; i < 128; ++i) {
        const int r = base + w + i * 8;
        if (r < KINST) {
            const float e = E[r];
            const short8_t v = *reinterpret_cast<const short8_t*>(H + (size_t)r * DIMEMB + lane * 8);
            #pragma unroll
            for (int j = 0; j < 8; ++j)
                a[j] += e * bf2f((unsigned short)v[j]);
        }
    }
    #pragma unroll
    for (int j = 0; j < 8; ++j) red[w][lane * 8 + j] = a[j];
    __syncthreads();
    float s = 0.f;
    #pragma unroll
    for (int k = 0; k < 8; ++k) s += red[k][tid];
    Mpart[blockIdx.x * 512 + tid] = s;
}

// ---------------- head: softmax-denominator, M, router, top-5, logits ----------------
__global__ __launch_bounds__(512) void k_head(
    const float* __restrict__ Spart,   // [782]
    const float* __restrict__ Mpart,   // [98][512]
    const float* __restrict__ Wr,      // [512][13]
    const float* __restrict__ Xtfl,    // [13][512]
    const float* __restrict__ Wp,      // [512][2]
    const float* __restrict__ bp,      // [2]
    float* __restrict__ outp)
{
    __shared__ float Mlds[512];
    __shared__ float logits[13];
    __shared__ float wsel[5];
    __shared__ int isel[5];
    __shared__ float Slds;
    __shared__ float swred[8];
    __shared__ float r0s[8], r1s[8];
    const int tid = threadIdx.x, lane = tid & 63, w = tid >> 6;

    float s = 0.f;
    for (int i = tid; i < 782; i += 512) s += Spart[i];
    #pragma unroll
    for (int off = 1; off < 64; off <<= 1) s += __shfl_xor(s, off, 64);
    if (lane == 0) swred[w] = s;

    float m = 0.f;
    for (int b = 0; b < 98; ++b) m += Mpart[b * 512 + tid];

    __syncthreads();
    if (tid == 0) {
        float t = 0.f;
        for (int i = 0; i < 8; ++i) t += swred[i];
        Slds = t;
    }
    __syncthreads();
    m /= Slds;
    Mlds[tid] = m;
    __syncthreads();
    if (tid < 13) {
        float l = 0.f;
        for (int d = 0; d < 512; ++d) l += Mlds[d] * Wr[d * 13 + tid];
        logits[tid] = l;
    }
    __syncthreads();
    if (tid == 0) {
        float mx = -1e30f;
        for (int i = 0; i < 13; ++i) mx = fmaxf(mx, logits[i]);
        float pe[13]; float sum = 0.f;
        for (int i = 0; i < 13; ++i) { pe[i] = expf(logits[i] - mx); sum += pe[i]; }
        unsigned used = 0;
        for (int t = 0; t < 5; ++t) {
            int bi = 0; float bv = -1.f;
            for (int i = 0; i < 13; ++i)
                if (!((used >> i) & 1u) && pe[i] > bv) { bv = pe[i]; bi = i; }
            used |= (1u << bi);
            wsel[t] = bv / sum;
            isel[t] = bi;
        }
    }
    __syncthreads();
    float mo = 0.f;
    #pragma unroll
    for (int t = 0; t < 5; ++t) mo += wsel[t] * Xtfl[isel[t] * 512 + tid];
    float p0 = mo * Wp[tid * 2 + 0];
    float p1 = mo * Wp[tid * 2 + 1];
    #pragma unroll
    for (int off = 1; off < 64; off <<= 1) {
        p0 += __shfl_xor(p0, off, 64);
        p1 += __shfl_xor(p1, off, 64);
    }
    if (lane == 0) { r0s[w] = p0; r1s[w] = p1; }
    __syncthreads();
    if (tid == 0) {
        float a = bp[0], b = bp[1];
        for (int i = 0; i < 8; ++i) { a += r0s[i]; b += r1s[i]; }
        outp[0] = a; outp[1] = b;
    }
}

extern "C" void kernel_launch(void* const* d_in, const int* in_sizes, int n_in,
                              void* d_out, int out_size, void* d_ws, size_t ws_size,
                              hipStream_t stream)
{
    const float* Xtfl  = (const float*)d_in[0];
    const float* X     = (const float*)d_in[1];
    const float* Wproj = (const float*)d_in[2];
    const float* bproj = (const float*)d_in[3];
    const float* W1    = (const float*)d_in[4];
    const float* b1    = (const float*)d_in[5];
    const float* W2    = (const float*)d_in[6];
    const float* b2    = (const float*)d_in[7];
    const float* Wr    = (const float*)d_in[8];
    const float* Wp    = (const float*)d_in[9];
    const float* bp    = (const float*)d_in[10];
    float* out = (float*)d_out;

    // ws layout (~100.3 MiB total)
    char* ws = (char*)d_ws;
    size_t off = 0;
    unsigned short* H   = (unsigned short*)(ws + off); off += (size_t)KPAD * DIMEMB * 2;   // 102,498,304
    unsigned short* WpT = (unsigned short*)(ws + off); off += (size_t)DIMEMB * DIMIN * 2;  //    786,432
    unsigned short* W1T = (unsigned short*)(ws + off); off += (size_t)DIMATTN * DIMEMB * 2;//    393,216
    float* E     = (float*)(ws + off); off += (size_t)KINST * 4;                           //    400,000
    float* Spart = (float*)(ws + off); off += 3200;                                        // 782 used
    float* Mpart = (float*)(ws + off); off += (size_t)98 * 512 * 4;

    k_prep<<<3072, 256, 0, stream>>>(Wproj, W1, WpT, W1T);
    dim3 g1(782, 4);
    k_gemm1<<<g1, 256, 0, stream>>>(X, WpT, bproj, H);
    k_gemm2<<<782, 512, 0, stream>>>(H, W1T, b1, W2, b2, E, Spart);
    k_pool<<<98, 512, 0, stream>>>(H, E, Mpart);
    k_head<<<1, 512, 0, stream>>>(Spart, Mpart, Wr, Xtfl, Wp, bp, out);
}

// Round 2
// 429.552 us; speedup vs baseline: 1.0245x; 1.0245x over previous
//
#include <hip/hip_runtime.h>
#include <hip/hip_bf16.h>

typedef __attribute__((ext_vector_type(8))) short short8_t;
typedef __attribute__((ext_vector_type(4))) float f32x4;
typedef __attribute__((ext_vector_type(4))) unsigned int u32x4;

#define KINST 100000
#define KPAD  100096   // 782 * 128
#define DIMIN 768
#define DIMEMB 512
#define DIMATTN 384

__device__ __forceinline__ unsigned short f2bf(float f) {
    unsigned int u = __builtin_bit_cast(unsigned int, f);
    u = u + 0x7FFFu + ((u >> 16) & 1u);       // RNE
    return (unsigned short)(u >> 16);
}
__device__ __forceinline__ unsigned int packbf(float a, float b) {
    return (unsigned int)f2bf(a) | ((unsigned int)f2bf(b) << 16);
}
__device__ __forceinline__ float bf2f(unsigned short h) {
    unsigned int u = ((unsigned int)h) << 16;
    return __builtin_bit_cast(float, u);
}
__device__ __forceinline__ float fast_tanh(float x) {
    const float e2 = __expf(2.f * x);
    return (e2 - 1.f) * __builtin_amdgcn_rcpf(e2 + 1.f);
}

// ---------------- prep: transposed/tiled bf16 weights ----------------
// WpTt layout: [t<12][n<512][c<64], element = bf16(Wproj[(t*64+c)*512 + n])
// W1T  layout: [n<384][k<512],      element = bf16(W1[k*384 + n])
__global__ __launch_bounds__(256) void k_prep(
    const float* __restrict__ Wproj, const float* __restrict__ W1,
    unsigned short* __restrict__ WpTt, unsigned short* __restrict__ W1T)
{
    const int idx = blockIdx.x * 256 + threadIdx.x;
    if (idx < DIMIN * DIMEMB) {                  // 393216, coalesced read of Wproj
        const int k = idx >> 9, n = idx & 511;
        const int t = k >> 6, c = k & 63;
        WpTt[t * 32768 + n * 64 + c] = f2bf(Wproj[idx]);
    } else {
        const int j = idx - DIMIN * DIMEMB;      // j < 196608
        const int n = j >> 9, k = j & 511;
        W1T[j] = f2bf(W1[k * DIMATTN + n]);
    }
}

// ---------------- GEMM1: H = relu(X @ Wp + b), bf16 out; BM=128, BN=512, BK=64 ----------------
__global__ __launch_bounds__(512) void k_gemm1(
    const float* __restrict__ X,
    const unsigned short* __restrict__ WpTt,
    const float* __restrict__ bproj,
    unsigned short* __restrict__ H)
{
    __shared__ unsigned short As[128][72];   // 18.4 KB, rows 144B (16B aligned)
    __shared__ unsigned short Bs[512][72];   // 73.7 KB
    const int tid = threadIdx.x;
    const int lane = tid & 63, w = tid >> 6;
    const int wr = w >> 2, wc = w & 3;       // 2x4 waves: 64 rows x 128 cols each
    const int g = lane >> 4, fr = lane & 15;
    const int brow = blockIdx.x * 128;

    f32x4 acc[4][8] = {};

    // A staging: thread -> (row = tid>>2, cols (tid&3)*16 .. +15)
    const int ar = tid >> 2;
    const int aq = (tid & 3) << 4;
    int agr = brow + ar; if (agr >= KINST) agr = KINST - 1;
    const float* Xrow = X + (size_t)agr * DIMIN;
    // B staging: thread stages row tid (64 bf16 = 128B, fully coalesced)
    const unsigned short* wsrc = WpTt + (size_t)tid * 64;

    for (int t = 0; t < 12; ++t) {
        {   // stage A: 128x64 fp32 -> bf16
            const float* xs = Xrow + t * 64 + aq;
            const float4 a0 = *(const float4*)(xs);
            const float4 a1 = *(const float4*)(xs + 4);
            const float4 a2 = *(const float4*)(xs + 8);
            const float4 a3 = *(const float4*)(xs + 12);
            u32x4 p0, p1;
            p0[0] = packbf(a0.x, a0.y); p0[1] = packbf(a0.z, a0.w);
            p0[2] = packbf(a1.x, a1.y); p0[3] = packbf(a1.z, a1.w);
            p1[0] = packbf(a2.x, a2.y); p1[1] = packbf(a2.z, a2.w);
            p1[2] = packbf(a3.x, a3.y); p1[3] = packbf(a3.z, a3.w);
            *(u32x4*)&As[ar][aq]     = p0;
            *(u32x4*)&As[ar][aq + 8] = p1;
        }
        {   // stage B: 512x64 bf16 copy
            const u32x4* bs = (const u32x4*)(wsrc + (size_t)t * 32768);
            #pragma unroll
            for (int c = 0; c < 8; ++c)
                *(u32x4*)&Bs[tid][c * 8] = bs[c];
        }
        __syncthreads();
        #pragma unroll
        for (int kk = 0; kk < 64; kk += 32) {
            const int krd = kk + g * 8;
            short8_t af[4];
            #pragma unroll
            for (int i = 0; i < 4; ++i)
                af[i] = *(const short8_t*)&As[wr * 64 + i * 16 + fr][krd];
            #pragma unroll
            for (int j = 0; j < 8; ++j) {
                const short8_t bfr = *(const short8_t*)&Bs[wc * 128 + j * 16 + fr][krd];
                #pragma unroll
                for (int i = 0; i < 4; ++i)
                    acc[i][j] = __builtin_amdgcn_mfma_f32_16x16x32_bf16(af[i], bfr, acc[i][j], 0, 0, 0);
            }
        }
        __syncthreads();
    }

    #pragma unroll
    for (int j = 0; j < 8; ++j) {
        const int col = wc * 128 + j * 16 + fr;
        const float bias = bproj[col];
        #pragma unroll
        for (int i = 0; i < 4; ++i) {
            const int rb = brow + wr * 64 + i * 16 + g * 4;
            #pragma unroll
            for (int r = 0; r < 4; ++r) {
                const int row = rb + r;
                const float v = fmaxf(acc[i][j][r] + bias, 0.f);
                H[(size_t)row * DIMEMB + col] = (row < KINST) ? f2bf(v) : (unsigned short)0;
            }
        }
    }
}

// -------- GEMM2 + attention score + fused pooling --------
// E_k = exp(tanh(H@W1+b1)@W2+b2); Spart[b] = sum E; Mpart[b][d] = sum E_k H[k][d]
__global__ __launch_bounds__(512) void k_gemm2(
    const unsigned short* __restrict__ H,
    const unsigned short* __restrict__ W1T,
    const float* __restrict__ b1,
    const float* __restrict__ W2,
    const float* __restrict__ b2,
    float* __restrict__ Spart,
    float* __restrict__ Mpart)
{
    __shared__ unsigned short Hs[128][40];
    __shared__ unsigned short Bs[384][40];
    __shared__ float sred[4][128];
    __shared__ float Elds[128];
    __shared__ float ssum[8];
    __shared__ float red[8][512];
    const int tid = threadIdx.x;
    const int lane = tid & 63, w = tid >> 6;
    const int wr = w >> 2, wc = w & 3;       // 2x4 waves: 64 rows x 96 cols each
    const int g = lane >> 4, fr = lane & 15;
    const int brow = blockIdx.x * 128;

    f32x4 acc[4][6] = {};

    for (int k0 = 0; k0 < DIMEMB; k0 += 32) {
        {   // Hs: 128x32 bf16
            const int ch = (tid & 3) << 3;
            const int r = tid >> 2;
            const u32x4 v = *(const u32x4*)(H + (size_t)(brow + r) * DIMEMB + k0 + ch);
            *(u32x4*)&Hs[r][ch] = v;
        }
        {   // Bs: 384x32 bf16 (3 chunks/thread)
            const int ch = (tid & 3) << 3;
            const int r0 = tid >> 2;
            #pragma unroll
            for (int p = 0; p < 3; ++p) {
                const int r = p * 128 + r0;
                const u32x4 v = *(const u32x4*)(W1T + (size_t)r * DIMEMB + k0 + ch);
                *(u32x4*)&Bs[r][ch] = v;
            }
        }
        __syncthreads();
        const int krd = g << 3;
        short8_t af[4];
        #pragma unroll
        for (int i = 0; i < 4; ++i)
            af[i] = *(const short8_t*)&Hs[wr * 64 + i * 16 + fr][krd];
        #pragma unroll
        for (int j = 0; j < 6; ++j) {
            const short8_t bfr = *(const short8_t*)&Bs[wc * 96 + j * 16 + fr][krd];
            #pragma unroll
            for (int i = 0; i < 4; ++i)
                acc[i][j] = __builtin_amdgcn_mfma_f32_16x16x32_bf16(af[i], bfr, acc[i][j], 0, 0, 0);
        }
        __syncthreads();
    }

    // per-lane partial score over this wave's 96 cols
    float ps[4][4] = {};
    #pragma unroll
    for (int j = 0; j < 6; ++j) {
        const int col = wc * 96 + j * 16 + fr;
        const float bb = b1[col], ww = W2[col];
        #pragma unroll
        for (int i = 0; i < 4; ++i)
            #pragma unroll
            for (int r = 0; r < 4; ++r)
                ps[i][r] += fast_tanh(acc[i][j][r] + bb) * ww;
    }
    #pragma unroll
    for (int off = 1; off < 16; off <<= 1)
        #pragma unroll
        for (int i = 0; i < 4; ++i)
            #pragma unroll
            for (int r = 0; r < 4; ++r)
                ps[i][r] += __shfl_xor(ps[i][r], off, 64);
    if (fr == 0) {
        #pragma unroll
        for (int i = 0; i < 4; ++i)
            #pragma unroll
            for (int r = 0; r < 4; ++r)
                sred[wc][wr * 64 + i * 16 + g * 4 + r] = ps[i][r];
    }
    __syncthreads();
    float myE = 0.f;
    if (tid < 128) {
        const int row = brow + tid;
        const float s = sred[0][tid] + sred[1][tid] + sred[2][tid] + sred[3][tid] + b2[0];
        const float e = __expf(s);
        const float eg = (row < KINST) ? e : 0.f;
        Elds[tid] = eg;
        myE = eg;
    }
    #pragma unroll
    for (int off = 1; off < 64; off <<= 1) myE += __shfl_xor(myE, off, 64);
    if (lane == 0) ssum[w] = myE;
    __syncthreads();
    if (tid == 0) {
        float t = 0.f;
        #pragma unroll
        for (int i = 0; i < 8; ++i) t += ssum[i];
        Spart[blockIdx.x] = t;
    }

    // fused pooling: re-read this block's H (L2-hot), weight by Elds
    float pa[8] = {};
    const int hb = lane << 3;
    #pragma unroll 4
    for (int i = 0; i < 16; ++i) {
        const int r = (w << 4) + i;
        const float e = Elds[r];
        const short8_t v = *(const short8_t*)(H + (size_t)(brow + r) * DIMEMB + hb);
        #pragma unroll
        for (int j = 0; j < 8; ++j)
            pa[j] += e * bf2f((unsigned short)v[j]);
    }
    #pragma unroll
    for (int j = 0; j < 8; ++j) red[w][hb + j] = pa[j];
    __syncthreads();
    float s2 = 0.f;
    #pragma unroll
    for (int k = 0; k < 8; ++k) s2 += red[k][tid];
    Mpart[(size_t)blockIdx.x * DIMEMB + tid] = s2;
}

// ---------------- head: reduce Spart/Mpart, router, top-5, logits ----------------
__global__ __launch_bounds__(1024) void k_head(
    const float* __restrict__ Spart,   // [782]
    const float* __restrict__ Mpart,   // [782][512]
    const float* __restrict__ Wr,      // [512][13]
    const float* __restrict__ Xtfl,    // [13][512]
    const float* __restrict__ Wp,      // [512][2]
    const float* __restrict__ bp,      // [2]
    float* __restrict__ outp)
{
    __shared__ float Mlds[512];
    __shared__ float red2[2][512];
    __shared__ float logits[13];
    __shared__ float wsel[5];
    __shared__ int isel[5];
    __shared__ float Slds;
    __shared__ float swred[16];
    __shared__ float r0s[16], r1s[16];
    const int tid = threadIdx.x, lane = tid & 63, w = tid >> 6;
    const int half = tid >> 9, d = tid & 511;

    float s = 0.f;
    for (int i = tid; i < 782; i += 1024) s += Spart[i];
    #pragma unroll
    for (int off = 1; off < 64; off <<= 1) s += __shfl_xor(s, off, 64);
    if (lane == 0) swred[w] = s;

    float m = 0.f;
    #pragma unroll 4
    for (int b = half; b < 782; b += 2) m += Mpart[(size_t)b * 512 + d];
    red2[half][d] = m;

    __syncthreads();
    if (tid == 0) {
        float t = 0.f;
        #pragma unroll
        for (int i = 0; i < 16; ++i) t += swred[i];
        Slds = t;
    }
    __syncthreads();
    if (tid < 512) {
        Mlds[tid] = (red2[0][tid] + red2[1][tid]) / Slds;
    }
    __syncthreads();
    if (tid < 13) {
        float l = 0.f;
        for (int dd = 0; dd < 512; ++dd) l += Mlds[dd] * Wr[dd * 13 + tid];
        logits[tid] = l;
    }
    __syncthreads();
    if (tid == 0) {
        float mx = -1e30f;
        for (int i = 0; i < 13; ++i) mx = fmaxf(mx, logits[i]);
        float pe[13]; float sum = 0.f;
        for (int i = 0; i < 13; ++i) { pe[i] = __expf(logits[i] - mx); sum += pe[i]; }
        unsigned used = 0;
        for (int t = 0; t < 5; ++t) {
            int bi = 0; float bv = -1.f;
            for (int i = 0; i < 13; ++i)
                if (!((used >> i) & 1u) && pe[i] > bv) { bv = pe[i]; bi = i; }
            used |= (1u << bi);
            wsel[t] = bv / sum;
            isel[t] = bi;
        }
    }
    __syncthreads();
    float p0 = 0.f, p1 = 0.f;
    if (tid < 512) {
        float mo = 0.f;
        #pragma unroll
        for (int t = 0; t < 5; ++t) mo += wsel[t] * Xtfl[isel[t] * 512 + tid];
        p0 = mo * Wp[tid * 2 + 0];
        p1 = mo * Wp[tid * 2 + 1];
    }
    #pragma unroll
    for (int off = 1; off < 64; off <<= 1) {
        p0 += __shfl_xor(p0, off, 64);
        p1 += __shfl_xor(p1, off, 64);
    }
    if (lane == 0) { r0s[w] = p0; r1s[w] = p1; }
    __syncthreads();
    if (tid == 0) {
        float a = bp[0], b = bp[1];
        for (int i = 0; i < 16; ++i) { a += r0s[i]; b += r1s[i]; }
        outp[0] = a; outp[1] = b;
    }
}

extern "C" void kernel_launch(void* const* d_in, const int* in_sizes, int n_in,
                              void* d_out, int out_size, void* d_ws, size_t ws_size,
                              hipStream_t stream)
{
    const float* Xtfl  = (const float*)d_in[0];
    const float* X     = (const float*)d_in[1];
    const float* Wproj = (const float*)d_in[2];
    const float* bproj = (const float*)d_in[3];
    const float* W1    = (const float*)d_in[4];
    const float* b1    = (const float*)d_in[5];
    const float* W2    = (const float*)d_in[6];
    const float* b2    = (const float*)d_in[7];
    const float* Wr    = (const float*)d_in[8];
    const float* Wp    = (const float*)d_in[9];
    const float* bp    = (const float*)d_in[10];
    float* out = (float*)d_out;

    // ws layout (~105 MiB total)
    char* ws = (char*)d_ws;
    size_t off = 0;
    unsigned short* H    = (unsigned short*)(ws + off); off += (size_t)KPAD * DIMEMB * 2;
    unsigned short* WpTt = (unsigned short*)(ws + off); off += (size_t)DIMEMB * DIMIN * 2;
    unsigned short* W1T  = (unsigned short*)(ws + off); off += (size_t)DIMATTN * DIMEMB * 2;
    float* Spart = (float*)(ws + off); off += 4096;
    float* Mpart = (float*)(ws + off); off += (size_t)782 * DIMEMB * 4;

    k_prep<<<2304, 256, 0, stream>>>(Wproj, W1, WpTt, W1T);
    k_gemm1<<<782, 512, 0, stream>>>(X, WpTt, bproj, H);
    k_gemm2<<<782, 512, 0, stream>>>(H, W1T, b1, W2, b2, Spart, Mpart);
    k_head<<<1, 1024, 0, stream>>>(Spart, Mpart, Wr, Xtfl, Wp, bp, out);
}